// Round 4
// baseline (161.922 us; speedup 1.0000x reference)
//
#include <hip/hip_runtime.h>
#include <hip/hip_bf16.h>

#define TN 768
#define DIM 768
#define NB 64
#define NA 51
#define POOL 128
#define THRESH 0.75f
#define LNEPS 1e-5f

typedef short s16x8 __attribute__((ext_vector_type(8)));
typedef float f32x4 __attribute__((ext_vector_type(4)));

typedef const __attribute__((address_space(1))) unsigned int* gas_p;
typedef __attribute__((address_space(3))) unsigned int* las_p;

__device__ __forceinline__ void gload16(const void* g, void* l) {
    // dest = lds base + lane*16 (wave-uniform base); src is per-lane
    __builtin_amdgcn_global_load_lds((gas_p)g, (las_p)l, 16, 0, 0);
}

__device__ inline unsigned short f2bf(float f) {
    union { float f; unsigned u; } v; v.f = f;
    unsigned r = v.u + 0x7fffu + ((v.u >> 16) & 1u);
    return (unsigned short)(r >> 16);
}

__constant__ int PAIR_I[21] = {0,1,1,2,2,2,3,3,3,3,4,4,4,4,4,5,5,5,5,5,5};
__constant__ int PAIR_J[21] = {0,0,1,0,1,2,0,1,2,3,0,1,2,3,4,0,1,2,3,4,5};

// ---- K1: per-token L2 norm + normalized bf16 copy (1 wave per token) ----
//      also zeroes bad[], Lval, done[] (replaces memset dispatches)
__global__ __launch_bounds__(256) void k_norms(const float* __restrict__ x,
                                               unsigned short* __restrict__ xn,
                                               float* __restrict__ norms,
                                               int* __restrict__ bad,
                                               int* __restrict__ Lval,
                                               int* __restrict__ done) {
    if (blockIdx.x < 192) bad[blockIdx.x * 256 + threadIdx.x] = 0;
    if (blockIdx.x == 0) {
        if (threadIdx.x == 0) *Lval = 0;
        if (threadIdx.x >= 64 && threadIdx.x < 64 + NA) done[threadIdx.x - 64] = 0;
    }

    const int tok  = blockIdx.x * 4 + (threadIdx.x >> 6);
    const int lane = threadIdx.x & 63;
    const float4* p = (const float4*)(x + (size_t)tok * DIM);
    float4 v[3];
    float s = 0.f;
#pragma unroll
    for (int q = 0; q < 3; ++q) {
        v[q] = p[q * 64 + lane];
        s += v[q].x * v[q].x + v[q].y * v[q].y + v[q].z * v[q].z + v[q].w * v[q].w;
    }
#pragma unroll
    for (int m = 1; m < 64; m <<= 1) s += __shfl_xor(s, m);
    const float nrm = sqrtf(s);
    const float sc = 1.0f / nrm;
#pragma unroll
    for (int q = 0; q < 3; ++q) {
        ushort4 u = { f2bf(v[q].x * sc), f2bf(v[q].y * sc),
                      f2bf(v[q].z * sc), f2bf(v[q].w * sc) };
        *(ushort4*)&xn[(size_t)tok * DIM + q * 256 + lane * 4] = u;
    }
    if (lane == 0) norms[tok] = nrm;
}

// ---- K2: gram tiles, triangle only; depth-2 counted-vmcnt pipeline ----
// 512 threads = 8 waves (4 row x 2 col), 3 LDS buffers, vmcnt(4) steady state
__global__ __launch_bounds__(512) void k_gram(const unsigned short* __restrict__ xn,
                                              int* __restrict__ bad) {
    const int f = blockIdx.x;                    // bijective XCD swizzle (1344 = 8*168)
    const int lid = (f & 7) * 168 + (f >> 3);
    const int b = lid / 21, p = lid - b * 21;
    const int it = PAIR_I[p], jt = PAIR_J[p];
    const bool diag = (it == jt);

    const int tid = threadIdx.x;
    const int lane = tid & 63, w = tid >> 6;     // w in 0..7
    const int lr = lane & 15;
    const int wr = w >> 1, wc = w & 1;           // 4x2 wave grid

    __shared__ alignas(16) unsigned short lA[3][128 * 64];   // 3 x 16 KB
    __shared__ alignas(16) unsigned short lB[3][128 * 64];   // 3 x 16 KB

    const char* xb = (const char*)(xn + (size_t)b * TN * DIM);
    // 1KB LDS segment = 8 rows x 128B; lane l -> row srow, granule (l&7).
    // Swizzled read addr = row*128 + 16*(g ^ (row&7)); XOR is an involution,
    // so pre-swizzle the global source, keep LDS dest linear (rule #21).
    const int srow = lane >> 3;
    const int sgoff = 16 * ((lane & 7) ^ (srow & 7));
    const size_t baseA = (size_t)(jt * 128 + srow) * 1536 + sgoff;
    const size_t baseB = (size_t)(it * 128 + srow) * 1536 + sgoff;

    f32x4 acc[2][4];
#pragma unroll
    for (int ff = 0; ff < 2; ++ff)
#pragma unroll
        for (int c = 0; c < 4; ++c) acc[ff][c] = {0.f, 0.f, 0.f, 0.f};

    auto stage = [&](int bb, int kk) {
#pragma unroll
        for (int i = 0; i < 2; ++i) {            // 2 A-segs per wave (16 total)
            const int seg = w * 2 + i;
            gload16(xb + baseA + (size_t)seg * 8 * 1536 + kk * 128,
                    (char*)lA[bb] + seg * 1024);
        }
        if (!diag) {
#pragma unroll
            for (int i = 0; i < 2; ++i) {
                const int seg = w * 2 + i;
                gload16(xb + baseB + (size_t)seg * 8 * 1536 + kk * 128,
                        (char*)lB[bb] + seg * 1024);
            }
        }
    };

    auto compute = [&](int bb) {
        const unsigned short* As = lA[bb];
        const unsigned short* Bs = diag ? lA[bb] : lB[bb];
        const int gx = 8 * (lr & 7);
#pragma unroll
        for (int kkk = 0; kkk < 2; ++kkk) {
            const int g = kkk * 4 + (lane >> 4);
            const int gs = (8 * g) ^ gx;
            const int r0 = wr * 32 + lr;
            s16x8 a0 = *(const s16x8*)&As[r0 * 64 + gs];
            s16x8 a1 = *(const s16x8*)&As[(r0 + 16) * 64 + gs];
#pragma unroll
            for (int c = 0; c < 4; ++c) {
                s16x8 bf = *(const s16x8*)&Bs[(wc * 64 + c * 16 + lr) * 64 + gs];
                acc[0][c] = __builtin_amdgcn_mfma_f32_16x16x32_bf16(a0, bf, acc[0][c], 0, 0, 0);
                acc[1][c] = __builtin_amdgcn_mfma_f32_16x16x32_bf16(a1, bf, acc[1][c], 0, 0, 0);
            }
        }
    };

#define WAIT_STEADY() do { if (diag) asm volatile("s_waitcnt vmcnt(2)" ::: "memory"); \
                           else      asm volatile("s_waitcnt vmcnt(4)" ::: "memory"); } while (0)

    // prologue: stage steps 0,1; wait for step 0 only (counted), barrier
    stage(0, 0);
    stage(1, 1);
    WAIT_STEADY();
    __builtin_amdgcn_s_barrier();

#pragma unroll
    for (int kk = 0; kk < 12; ++kk) {
        if (kk < 10) stage((kk + 2) % 3, kk + 2);
        compute(kk % 3);
        if (kk < 11) {
            if (kk < 10) WAIT_STEADY();
            else asm volatile("s_waitcnt vmcnt(0)" ::: "memory");
            __builtin_amdgcn_s_barrier();
        }
    }
#undef WAIT_STEADY

    // C/D layout: col = lane&15, row = (lane>>4)*4 + reg   [m89/m91]
#pragma unroll
    for (int ff = 0; ff < 2; ++ff) {
#pragma unroll
        for (int r = 0; r < 4; ++r) {
            const int rowg = jt * 128 + wr * 32 + ff * 16 + (lane >> 4) * 4 + r;
            bool any = false;
#pragma unroll
            for (int c = 0; c < 4; ++c) {
                const int colg = it * 128 + wc * 64 + c * 16 + lr;
                any = any || (acc[ff][c][r] > THRESH && rowg != colg);
            }
            if (any) bad[b * TN + rowg] = 1;     // benign race: all writers store 1
        }
    }
    if (!diag) {   // symmetry: flag columns too (their row view is this tile^T)
#pragma unroll
        for (int c = 0; c < 4; ++c) {
            const int colg = it * 128 + wc * 64 + c * 16 + lr;
            bool any = false;
#pragma unroll
            for (int ff = 0; ff < 2; ++ff)
#pragma unroll
                for (int r = 0; r < 4; ++r)
                    any = any || (acc[ff][c][r] > THRESH);
            if (any) bad[b * TN + colg] = 1;
        }
    }
}

// ---- K3: keep-count, top-k fallback (rank w/ index tiebreak), compaction ----
__global__ __launch_bounds__(256) void k_filter(const int* __restrict__ bad,
                                                const float* __restrict__ norms,
                                                int* __restrict__ inv,
                                                int* __restrict__ counts,
                                                int* __restrict__ Lval) {
    const int b = blockIdx.x, t = threadIdx.x;
    __shared__ float nsh[TN];
    __shared__ unsigned char ksh[TN];
    __shared__ int scan[256];

    for (int j = t; j < TN; j += 256) nsh[j] = norms[b * TN + j];
    const int j0 = t * 3;
#pragma unroll
    for (int q = 0; q < 3; ++q) ksh[j0 + q] = bad[b * TN + j0 + q] ? 0 : 1;
    __syncthreads();

    for (int round = 0; round < 2; ++round) {
        int local = ksh[j0] + ksh[j0 + 1] + ksh[j0 + 2];
        scan[t] = local;
        __syncthreads();
        for (int off = 1; off < 256; off <<= 1) {
            int v = (t >= off) ? scan[t - off] : 0;
            __syncthreads();
            scan[t] += v;
            __syncthreads();
        }
        int total = scan[255];
        if (round == 0 && total < POOL) {
            for (int q = 0; q < 3; ++q) {
                int j = j0 + q;
                float nj = nsh[j];
                int rank = 0;
                for (int i = 0; i < TN; ++i) {
                    float ni = nsh[i];
                    rank += (ni > nj) || (ni == nj && i < j);
                }
                ksh[j] = (rank < POOL) ? 1 : 0;
            }
            __syncthreads();
            continue;
        }
        int pos = scan[t] - local;
        for (int q = 0; q < 3; ++q) {
            int j = j0 + q;
            if (ksh[j]) inv[b * TN + pos++] = j;
        }
        if (t == 0) { counts[b] = total; atomicMax(Lval, total); }
        break;
    }
}

// ---- K4: pooled row + LayerNorm + attr head dot + fused BatchNorm tail ----
__device__ inline float block_sum(float v, volatile float* sred, int t) {
#pragma unroll
    for (int m = 1; m < 64; m <<= 1) v += __shfl_xor(v, m);
    if ((t & 63) == 0) sred[t >> 6] = v;
    __syncthreads();
    float r = sred[0] + sred[1] + sred[2] + sred[3];
    __syncthreads();
    return r;
}

__global__ __launch_bounds__(256) void k_head(const float* __restrict__ x,
                                              const int* __restrict__ inv,
                                              const int* __restrict__ counts,
                                              const int* __restrict__ Lval,
                                              const float* __restrict__ lng,
                                              const float* __restrict__ lnb,
                                              const float* __restrict__ wat,
                                              const float* __restrict__ bat,
                                              const float* __restrict__ bng,
                                              const float* __restrict__ bnb,
                                              float* __restrict__ logits,
                                              int* __restrict__ done,
                                              float* __restrict__ out) {
    const int a = blockIdx.x, b = blockIdx.y, t = threadIdx.x;
    __shared__ float sred[4];
    __shared__ int amlast;
    const int L = *Lval, cnt = counts[b];
    const int start = (a * L) >> 7;
    const int end = ((a + 1) * L + 127) >> 7;
    const int wdt = end - start;
    const int pe = min(end, cnt);

    float a0 = 0.f, a1 = 0.f, a2 = 0.f;
    for (int p = start; p < pe; ++p) {
        const float* row = x + (size_t)(b * TN + inv[b * TN + p]) * DIM;
        a0 += row[t]; a1 += row[t + 256]; a2 += row[t + 512];
    }
    const float iw = 1.0f / (float)wdt;
    a0 *= iw; a1 *= iw; a2 *= iw;

    float s1 = block_sum(a0 + a1 + a2, sred, t);
    float s2 = block_sum(a0 * a0 + a1 * a1 + a2 * a2, sred, t);
    const float mu = s1 * (1.0f / 768.0f);
    const float var = s2 * (1.0f / 768.0f) - mu * mu;
    const float rstd = rsqrtf(var + LNEPS);

    const float* wa = wat + (size_t)a * DIM;
    float d = ((a0 - mu) * rstd * lng[t]       + lnb[t])       * wa[t]
            + ((a1 - mu) * rstd * lng[t + 256] + lnb[t + 256]) * wa[t + 256]
            + ((a2 - mu) * rstd * lng[t + 512] + lnb[t + 512]) * wa[t + 512];
    float dot = block_sum(d, sred, t);

    if (t == 0) {
        atomicExch(&logits[b * NA + a], dot + bat[a]);   // coherent store
        __threadfence();                                  // release
        int old = atomicAdd(&done[a], 1);
        amlast = (old == NB - 1);
    }
    __syncthreads();
    if (!amlast || t >= 64) return;

    // last block for this attribute: BatchNorm over the batch (one wave)
    __threadfence();                                      // acquire
    float v = atomicAdd(&logits[t * NA + a], 0.0f);       // coherent load
    float s = v, sq = v * v;
#pragma unroll
    for (int m = 1; m < 64; m <<= 1) {
        s  += __shfl_xor(s, m);
        sq += __shfl_xor(sq, m);
    }
    const float bm = s * (1.0f / 64.0f);
    const float bv = sq * (1.0f / 64.0f) - bm * bm;
    const float brs = rsqrtf(bv + LNEPS);
    out[t * NA + a] = (v - bm) * brs * bng[a] + bnb[a];
}

extern "C" void kernel_launch(void* const* d_in, const int* in_sizes, int n_in,
                              void* d_out, int out_size, void* d_ws, size_t ws_size,
                              hipStream_t stream) {
    const float* x     = (const float*)d_in[0];
    const float* ln_g  = (const float*)d_in[1];
    const float* ln_b  = (const float*)d_in[2];
    const float* w_at  = (const float*)d_in[3];
    const float* b_at  = (const float*)d_in[4];
    const float* bn_g  = (const float*)d_in[5];
    const float* bn_b  = (const float*)d_in[6];
    float* out = (float*)d_out;

    char* wsc = (char*)d_ws;
    const size_t XN = 64ull * 768 * 768 * 2;          // 75,497,472 B bf16 copy
    unsigned short* xn = (unsigned short*)wsc;
    float* norms  = (float*)(wsc + XN);                // 196608 B
    int*   bad    = (int*)(wsc + XN + 196608);         // 196608 B
    int*   inv    = (int*)(wsc + XN + 393216);         // 196608 B
    int*   counts = (int*)(wsc + XN + 589824);         // 256 B
    int*   Lval   = (int*)(wsc + XN + 590080);         // 256 B
    float* logits = (float*)(wsc + XN + 590336);       // 13056 B
    int*   done   = (int*)(wsc + XN + 603392);         // 204 B

    k_norms <<<NB * TN / 4, 256, 0, stream>>>(x, xn, norms, bad, Lval, done);
    k_gram  <<<21 * NB, 512, 0, stream>>>(xn, bad);
    k_filter<<<NB, 256, 0, stream>>>(bad, norms, inv, counts, Lval);
    k_head  <<<dim3(NA, NB), 256, 0, stream>>>(x, inv, counts, Lval,
                                               ln_g, ln_b, w_at, b_at,
                                               bn_g, bn_b, logits, done, out);
}

// Round 5
// 132.899 us; speedup vs baseline: 1.2184x; 1.2184x over previous
//
#include <hip/hip_runtime.h>
#include <hip/hip_bf16.h>

#define TN 768
#define DIM 768
#define NB 64
#define NA 51
#define POOL 128
#define THRESH 0.75f
#define LNEPS 1e-5f

typedef float f32x4 __attribute__((ext_vector_type(4)));

typedef const __attribute__((address_space(1))) unsigned int* gas_p;
typedef __attribute__((address_space(3))) unsigned int* las_p;

__device__ __forceinline__ void gload16(const void* g, void* l) {
    // dest = lds base + lane*16 (wave-uniform base); src is per-lane
    __builtin_amdgcn_global_load_lds((gas_p)g, (las_p)l, 16, 0, 0);
}

__constant__ int PAIR_I[21] = {0,1,1,2,2,2,3,3,3,3,4,4,4,4,4,5,5,5,5,5,5};
__constant__ int PAIR_J[21] = {0,0,1,0,1,2,0,1,2,3,0,1,2,3,4,0,1,2,3,4,5};

// ---- K1: per-token L2 norm + normalized fp8(e4m3) copy (1 wave/token) ----
//      also zeroes bad[], Lval, done[] (replaces memset dispatches)
__global__ __launch_bounds__(256) void k_norms(const float* __restrict__ x,
                                               unsigned int* __restrict__ xn,
                                               float* __restrict__ norms,
                                               int* __restrict__ bad,
                                               int* __restrict__ Lval,
                                               int* __restrict__ done) {
    if (blockIdx.x < 192) bad[blockIdx.x * 256 + threadIdx.x] = 0;
    if (blockIdx.x == 0) {
        if (threadIdx.x == 0) *Lval = 0;
        if (threadIdx.x >= 64 && threadIdx.x < 64 + NA) done[threadIdx.x - 64] = 0;
    }

    const int tok  = blockIdx.x * 4 + (threadIdx.x >> 6);
    const int lane = threadIdx.x & 63;
    const float4* p = (const float4*)(x + (size_t)tok * DIM);
    float4 v[3];
    float s = 0.f;
#pragma unroll
    for (int q = 0; q < 3; ++q) {
        v[q] = p[q * 64 + lane];
        s += v[q].x * v[q].x + v[q].y * v[q].y + v[q].z * v[q].z + v[q].w * v[q].w;
    }
#pragma unroll
    for (int m = 1; m < 64; m <<= 1) s += __shfl_xor(s, m);
    const float nrm = sqrtf(s);
    const float sc = 1.0f / nrm;
#pragma unroll
    for (int q = 0; q < 3; ++q) {
        int w0 = __builtin_amdgcn_cvt_pk_fp8_f32(v[q].x * sc, v[q].y * sc, 0, false);
        w0     = __builtin_amdgcn_cvt_pk_fp8_f32(v[q].z * sc, v[q].w * sc, w0, true);
        xn[(size_t)tok * 192 + q * 64 + lane] = (unsigned)w0;
    }
    if (lane == 0) norms[tok] = nrm;
}

// ---- K2: fp8 gram tiles, triangle only (21 pairs), 2-phase dbuf pipeline ----
// Round-3-proven structure: 256 thr, 2 buffers (64 KB), 2 blocks/CU.
// fp8 BK=128 elems (=128B row): 6 K-steps, half the bytes/barriers of bf16.
__global__ __launch_bounds__(256) void k_gram(const unsigned char* __restrict__ xn,
                                              int* __restrict__ bad) {
    // bijective XCD swizzle: 1344 blocks = 8 XCD x 168; same-b blocks cluster
    const int f = blockIdx.x;
    const int lid = (f & 7) * 168 + (f >> 3);
    const int b = lid / 21, p = lid - b * 21;
    const int it = PAIR_I[p], jt = PAIR_J[p];
    const bool diag = (it == jt);

    const int tid = threadIdx.x;
    const int lane = tid & 63, w = tid >> 6;
    const int lr = lane & 15;

    __shared__ alignas(16) unsigned char lA[2][128 * 128];   // 2 x 16 KB
    __shared__ alignas(16) unsigned char lB[2][128 * 128];

    const unsigned char* xb = xn + (size_t)b * TN * DIM;   // 768 B per token
    // 1KB LDS segment = 8 rows x 128B; lane l -> row srow, 16B granule (l&7).
    // Swizzled read addr = row*128 + 16*(g ^ (row&7)) [+8*half]; XOR is an
    // involution -> pre-swizzle global source, keep LDS dest linear (rule #21).
    const int srow = lane >> 3;
    const int sgoff = 16 * ((lane & 7) ^ (srow & 7));
    const size_t baseA = (size_t)(jt * 128 + srow) * DIM + sgoff;
    const size_t baseB = (size_t)(it * 128 + srow) * DIM + sgoff;

    f32x4 acc[2][8];
#pragma unroll
    for (int ff = 0; ff < 2; ++ff)
#pragma unroll
        for (int c = 0; c < 8; ++c) acc[ff][c] = {0.f, 0.f, 0.f, 0.f};

    auto stage = [&](int bb, int kk) {
#pragma unroll
        for (int i = 0; i < 4; ++i) {            // 4 segs/wave = 16 segs = 16 KB
            const int seg = w * 4 + i;
            gload16(xb + baseA + (size_t)seg * 8 * DIM + kk * 128,
                    (char*)lA[bb] + seg * 1024);
        }
        if (!diag) {
#pragma unroll
            for (int i = 0; i < 4; ++i) {
                const int seg = w * 4 + i;
                gload16(xb + baseB + (size_t)seg * 8 * DIM + kk * 128,
                        (char*)lB[bb] + seg * 1024);
            }
        }
    };

    auto compute = [&](int bb) {
        const unsigned char* As = lA[bb];
        const unsigned char* Bs = diag ? lA[bb] : lB[bb];
        const int lt = lane >> 4;                // 0..3: k-chunk of 8 bytes
        const int half8 = (lt & 1) * 8;
        const int gx = lr & 7;                   // (row&7) for all frag rows
#pragma unroll
        for (int kkk = 0; kkk < 4; ++kkk) {      // 4 x K=32 per 128-B step
            const int g16 = kkk * 2 + (lt >> 1);
            const int goff = 16 * (g16 ^ gx) + half8;
            const int r0 = w * 32 + lr;
            long a0 = *(const long*)&As[r0 * 128 + goff];
            long a1 = *(const long*)&As[(r0 + 16) * 128 + goff];
#pragma unroll
            for (int c = 0; c < 8; ++c) {
                long bf = *(const long*)&Bs[(c * 16 + lr) * 128 + goff];
                acc[0][c] = __builtin_amdgcn_mfma_f32_16x16x32_fp8_fp8(a0, bf, acc[0][c], 0, 0, 0);
                acc[1][c] = __builtin_amdgcn_mfma_f32_16x16x32_fp8_fp8(a1, bf, acc[1][c], 0, 0, 0);
            }
        }
    };

    // 2-phase pipeline: stage(next) || compute(cur); one vmcnt(0)+barrier/step
    stage(0, 0);
    asm volatile("s_waitcnt vmcnt(0)" ::: "memory");
    __builtin_amdgcn_s_barrier();
#pragma unroll
    for (int kk = 0; kk < 6; ++kk) {
        const int cur = kk & 1;
        if (kk < 5) stage(cur ^ 1, kk + 1);
        compute(cur);
        if (kk < 5) {
            asm volatile("s_waitcnt vmcnt(0)" ::: "memory");
            __builtin_amdgcn_s_barrier();
        }
    }

    // C/D layout (dtype-independent, m121-128): col = lane&15, row = (lane>>4)*4 + reg
#pragma unroll
    for (int ff = 0; ff < 2; ++ff) {
#pragma unroll
        for (int r = 0; r < 4; ++r) {
            const int rowg = jt * 128 + w * 32 + ff * 16 + (lane >> 4) * 4 + r;
            bool any = false;
#pragma unroll
            for (int c = 0; c < 8; ++c) {
                const int colg = it * 128 + c * 16 + lr;
                any = any || (acc[ff][c][r] > THRESH && rowg != colg);
            }
            if (any) bad[b * TN + rowg] = 1;   // benign race: all writers store 1
        }
    }
    if (!diag) {   // symmetry: flag columns too (their row view is this tile^T)
#pragma unroll
        for (int c = 0; c < 8; ++c) {
            const int colg = it * 128 + c * 16 + lr;
            bool any = false;
#pragma unroll
            for (int ff = 0; ff < 2; ++ff)
#pragma unroll
                for (int r = 0; r < 4; ++r)
                    any = any || (acc[ff][c][r] > THRESH);
            if (any) bad[b * TN + colg] = 1;
        }
    }
}

// ---- K3: keep-count, top-k fallback (rank w/ index tiebreak), compaction ----
__global__ __launch_bounds__(256) void k_filter(const int* __restrict__ bad,
                                                const float* __restrict__ norms,
                                                int* __restrict__ inv,
                                                int* __restrict__ counts,
                                                int* __restrict__ Lval) {
    const int b = blockIdx.x, t = threadIdx.x;
    __shared__ float nsh[TN];
    __shared__ unsigned char ksh[TN];
    __shared__ int scan[256];

    for (int j = t; j < TN; j += 256) nsh[j] = norms[b * TN + j];
    const int j0 = t * 3;
#pragma unroll
    for (int q = 0; q < 3; ++q) ksh[j0 + q] = bad[b * TN + j0 + q] ? 0 : 1;
    __syncthreads();

    for (int round = 0; round < 2; ++round) {
        int local = ksh[j0] + ksh[j0 + 1] + ksh[j0 + 2];
        scan[t] = local;
        __syncthreads();
        for (int off = 1; off < 256; off <<= 1) {
            int v = (t >= off) ? scan[t - off] : 0;
            __syncthreads();
            scan[t] += v;
            __syncthreads();
        }
        int total = scan[255];
        if (round == 0 && total < POOL) {
            for (int q = 0; q < 3; ++q) {
                int j = j0 + q;
                float nj = nsh[j];
                int rank = 0;
                for (int i = 0; i < TN; ++i) {
                    float ni = nsh[i];
                    rank += (ni > nj) || (ni == nj && i < j);
                }
                ksh[j] = (rank < POOL) ? 1 : 0;
            }
            __syncthreads();
            continue;
        }
        int pos = scan[t] - local;
        for (int q = 0; q < 3; ++q) {
            int j = j0 + q;
            if (ksh[j]) inv[b * TN + pos++] = j;
        }
        if (t == 0) { counts[b] = total; atomicMax(Lval, total); }
        break;
    }
}

// ---- K4: pooled row + LayerNorm + attr head dot + fused BatchNorm tail ----
__device__ inline float block_sum(float v, volatile float* sred, int t) {
#pragma unroll
    for (int m = 1; m < 64; m <<= 1) v += __shfl_xor(v, m);
    if ((t & 63) == 0) sred[t >> 6] = v;
    __syncthreads();
    float r = sred[0] + sred[1] + sred[2] + sred[3];
    __syncthreads();
    return r;
}

__global__ __launch_bounds__(256) void k_head(const float* __restrict__ x,
                                              const int* __restrict__ inv,
                                              const int* __restrict__ counts,
                                              const int* __restrict__ Lval,
                                              const float* __restrict__ lng,
                                              const float* __restrict__ lnb,
                                              const float* __restrict__ wat,
                                              const float* __restrict__ bat,
                                              const float* __restrict__ bng,
                                              const float* __restrict__ bnb,
                                              float* __restrict__ logits,
                                              int* __restrict__ done,
                                              float* __restrict__ out) {
    const int a = blockIdx.x, b = blockIdx.y, t = threadIdx.x;
    __shared__ float sred[4];
    __shared__ int amlast;
    const int L = *Lval, cnt = counts[b];
    const int start = (a * L) >> 7;
    const int end = ((a + 1) * L + 127) >> 7;
    const int wdt = end - start;
    const int pe = min(end, cnt);

    float a0 = 0.f, a1 = 0.f, a2 = 0.f;
    for (int p = start; p < pe; ++p) {
        const float* row = x + (size_t)(b * TN + inv[b * TN + p]) * DIM;
        a0 += row[t]; a1 += row[t + 256]; a2 += row[t + 512];
    }
    const float iw = 1.0f / (float)wdt;
    a0 *= iw; a1 *= iw; a2 *= iw;

    float s1 = block_sum(a0 + a1 + a2, sred, t);
    float s2 = block_sum(a0 * a0 + a1 * a1 + a2 * a2, sred, t);
    const float mu = s1 * (1.0f / 768.0f);
    const float var = s2 * (1.0f / 768.0f) - mu * mu;
    const float rstd = rsqrtf(var + LNEPS);

    const float* wa = wat + (size_t)a * DIM;
    float d = ((a0 - mu) * rstd * lng[t]       + lnb[t])       * wa[t]
            + ((a1 - mu) * rstd * lng[t + 256] + lnb[t + 256]) * wa[t + 256]
            + ((a2 - mu) * rstd * lng[t + 512] + lnb[t + 512]) * wa[t + 512];
    float dot = block_sum(d, sred, t);

    if (t == 0) {
        atomicExch(&logits[b * NA + a], dot + bat[a]);   // coherent store
        __threadfence();                                  // release
        int old = atomicAdd(&done[a], 1);
        amlast = (old == NB - 1);
    }
    __syncthreads();
    if (!amlast || t >= 64) return;

    // last block for this attribute: BatchNorm over the batch (one wave)
    __threadfence();                                      // acquire
    float v = atomicAdd(&logits[t * NA + a], 0.0f);       // coherent load
    float s = v, sq = v * v;
#pragma unroll
    for (int m = 1; m < 64; m <<= 1) {
        s  += __shfl_xor(s, m);
        sq += __shfl_xor(sq, m);
    }
    const float bm = s * (1.0f / 64.0f);
    const float bv = sq * (1.0f / 64.0f) - bm * bm;
    const float brs = rsqrtf(bv + LNEPS);
    out[t * NA + a] = (v - bm) * brs * bng[a] + bnb[a];
}

extern "C" void kernel_launch(void* const* d_in, const int* in_sizes, int n_in,
                              void* d_out, int out_size, void* d_ws, size_t ws_size,
                              hipStream_t stream) {
    const float* x     = (const float*)d_in[0];
    const float* ln_g  = (const float*)d_in[1];
    const float* ln_b  = (const float*)d_in[2];
    const float* w_at  = (const float*)d_in[3];
    const float* b_at  = (const float*)d_in[4];
    const float* bn_g  = (const float*)d_in[5];
    const float* bn_b  = (const float*)d_in[6];
    float* out = (float*)d_out;

    char* wsc = (char*)d_ws;
    const size_t XN = 64ull * 768 * 768;               // 37,748,736 B fp8 copy
    unsigned char* xn = (unsigned char*)wsc;
    float* norms  = (float*)(wsc + XN);                // 196608 B
    int*   bad    = (int*)(wsc + XN + 196608);         // 196608 B
    int*   inv    = (int*)(wsc + XN + 393216);         // 196608 B
    int*   counts = (int*)(wsc + XN + 589824);         // 256 B
    int*   Lval   = (int*)(wsc + XN + 590080);         // 256 B
    float* logits = (float*)(wsc + XN + 590336);       // 13056 B
    int*   done   = (int*)(wsc + XN + 603392);         // 204 B

    k_norms <<<NB * TN / 4, 256, 0, stream>>>(x, (unsigned int*)xn, norms, bad, Lval, done);
    k_gram  <<<21 * NB, 256, 0, stream>>>(xn, bad);
    k_filter<<<NB, 256, 0, stream>>>(bad, norms, inv, counts, Lval);
    k_head  <<<dim3(NA, NB), 256, 0, stream>>>(x, inv, counts, Lval,
                                               ln_g, ln_b, w_at, b_at,
                                               bn_g, bn_b, logits, done, out);
}

// Round 6
// 80.034 us; speedup vs baseline: 2.0232x; 1.6605x over previous
//
#include <hip/hip_runtime.h>
#include <hip/hip_bf16.h>

#define TN 768
#define DIM 768
#define NB 64
#define NA 51
#define POOL 128
#define THRESH 0.75f
#define LNEPS 1e-5f

typedef float f32x4 __attribute__((ext_vector_type(4)));
typedef long l64x2 __attribute__((ext_vector_type(2)));

typedef const __attribute__((address_space(1))) unsigned int* gas_p;
typedef __attribute__((address_space(3))) unsigned int* las_p;

__device__ __forceinline__ void gload16(const void* g, void* l) {
    // dest = lds base + lane*16 (wave-uniform base); src is per-lane
    __builtin_amdgcn_global_load_lds((gas_p)g, (las_p)l, 16, 0, 0);
}

__constant__ int PAIR_I[21] = {0,1,1,2,2,2,3,3,3,3,4,4,4,4,4,5,5,5,5,5,5};
__constant__ int PAIR_J[21] = {0,0,1,0,1,2,0,1,2,3,0,1,2,3,4,0,1,2,3,4,5};

// ---- K1: per-token L2 norm + normalized fp8(e4m3) copy, PERMUTED layout ----
// Within each 128B k-block: source byte kb = 32c+8s+r  (c=K32 chunk, s=lane
// group slot, r in-slot) is stored at pos = 16*(4*(c>>1)+s) + 8*(c&1) + r.
// => LDS granule g = 4q+s is one ds_read_b128: lo 8B = chunk 2q, hi = 2q+1,
//    both for lane-group s. Also zeroes bad[] and Lval.
__global__ __launch_bounds__(256) void k_norms(const float* __restrict__ x,
                                               unsigned int* __restrict__ xn,
                                               float* __restrict__ norms,
                                               int* __restrict__ bad,
                                               int* __restrict__ Lval) {
    if (blockIdx.x < 192) bad[blockIdx.x * 256 + threadIdx.x] = 0;
    if (blockIdx.x == 0 && threadIdx.x == 0) *Lval = 0;

    const int tok  = blockIdx.x * 4 + (threadIdx.x >> 6);
    const int lane = threadIdx.x & 63;
    const float4* p = (const float4*)(x + (size_t)tok * DIM);
    float4 v[3];
    float s = 0.f;
#pragma unroll
    for (int q = 0; q < 3; ++q) {
        v[q] = p[q * 64 + lane];
        s += v[q].x * v[q].x + v[q].y * v[q].y + v[q].z * v[q].z + v[q].w * v[q].w;
    }
#pragma unroll
    for (int m = 1; m < 64; m <<= 1) s += __shfl_xor(s, m);
    const float nrm = sqrtf(s);
    const float sc = 1.0f / nrm;
    unsigned int* xrow = xn + (size_t)tok * 192;        // 768 B / 4
#pragma unroll
    for (int q = 0; q < 3; ++q) {
        int w0 = __builtin_amdgcn_cvt_pk_fp8_f32(v[q].x * sc, v[q].y * sc, 0, false);
        w0     = __builtin_amdgcn_cvt_pk_fp8_f32(v[q].z * sc, v[q].w * sc, w0, true);
        const int k  = q * 256 + lane * 4;              // byte index in row
        const int kb = k & 127;
        const int c  = kb >> 5, sl = (kb >> 3) & 3, r = kb & 7;
        const int pos = (k & ~127) + 16 * (4 * (c >> 1) + sl) + 8 * (c & 1) + r;
        xrow[pos >> 2] = (unsigned)w0;
    }
    if (lane == 0) norms[tok] = nrm;
}

// ---- K2: fp8 gram tiles, triangle (21 pairs), 2-phase dbuf, 64x64 wave tiles ----
// 256 thr (2x2 wave grid), 64 KB LDS (2 blocks/CU), 6 K-steps of 128 fp8.
__global__ __launch_bounds__(256) void k_gram(const unsigned char* __restrict__ xn,
                                              int* __restrict__ bad) {
    // bijective XCD swizzle: 1344 blocks = 8 XCD x 168
    const int f = blockIdx.x;
    const int lid = (f & 7) * 168 + (f >> 3);
    const int b = lid / 21, p = lid - b * 21;
    const int it = PAIR_I[p], jt = PAIR_J[p];
    const bool diag = (it == jt);

    const int tid = threadIdx.x;
    const int lane = tid & 63, w = tid >> 6;
    const int lr = lane & 15, lt = lane >> 4;
    const int wr = w >> 1, wc = w & 1;                  // 2x2 wave grid

    __shared__ alignas(16) unsigned char lA[2][128 * 128];   // 2 x 16 KB
    __shared__ alignas(16) unsigned char lB[2][128 * 128];

    const unsigned char* xb = xn + (size_t)b * TN * DIM;     // 768 B / token
    // stage: 1KB LDS segment = 8 rows x 128B; lane l -> row (l>>3), granule
    // (l&7). LDS[row][g] = SRC[row][g ^ (row&7)]  (pre-swizzled source,
    // linear dest -- rule #21). Compute reads granule (4q+lt)^(row&7) -> the
    // content is source granule 4q+lt = permuted (q, slot=lt) pair.
    const int srow = lane >> 3;
    const int sgoff = 16 * ((lane & 7) ^ (srow & 7));
    const size_t baseA = (size_t)(jt * 128 + srow) * DIM + sgoff;
    const size_t baseB = (size_t)(it * 128 + srow) * DIM + sgoff;

    f32x4 acc[4][4];
#pragma unroll
    for (int m = 0; m < 4; ++m)
#pragma unroll
        for (int n = 0; n < 4; ++n) acc[m][n] = {0.f, 0.f, 0.f, 0.f};

    auto stage = [&](int bb, int kk) {
#pragma unroll
        for (int i = 0; i < 4; ++i) {            // 4 segs/wave = 16 segs = 16 KB
            const int seg = w * 4 + i;
            gload16(xb + baseA + (size_t)seg * 8 * DIM + kk * 128,
                    (char*)lA[bb] + seg * 1024);
        }
        if (!diag) {
#pragma unroll
            for (int i = 0; i < 4; ++i) {
                const int seg = w * 4 + i;
                gload16(xb + baseB + (size_t)seg * 8 * DIM + kk * 128,
                        (char*)lB[bb] + seg * 1024);
            }
        }
    };

    auto compute = [&](int bb) {
        const unsigned char* As = lA[bb];
        const unsigned char* Bs = diag ? lA[bb] : lB[bb];
        const int gx = lr & 7;
#pragma unroll
        for (int q = 0; q < 2; ++q) {
            const int goff = 16 * ((4 * q + lt) ^ gx);
            l64x2 a[4], bv[4];
#pragma unroll
            for (int m = 0; m < 4; ++m)
                a[m] = *(const l64x2*)&As[(wr * 64 + m * 16 + lr) * 128 + goff];
#pragma unroll
            for (int n = 0; n < 4; ++n)
                bv[n] = *(const l64x2*)&Bs[(wc * 64 + n * 16 + lr) * 128 + goff];
#pragma unroll
            for (int m = 0; m < 4; ++m)
#pragma unroll
                for (int n = 0; n < 4; ++n) {
                    acc[m][n] = __builtin_amdgcn_mfma_f32_16x16x32_fp8_fp8(a[m][0], bv[n][0], acc[m][n], 0, 0, 0);
                    acc[m][n] = __builtin_amdgcn_mfma_f32_16x16x32_fp8_fp8(a[m][1], bv[n][1], acc[m][n], 0, 0, 0);
                }
        }
    };

    // 2-phase pipeline: stage(next) || compute(cur); one vmcnt(0)+barrier/step
    stage(0, 0);
    asm volatile("s_waitcnt vmcnt(0)" ::: "memory");
    __builtin_amdgcn_s_barrier();
#pragma unroll
    for (int kk = 0; kk < 6; ++kk) {
        const int cur = kk & 1;
        if (kk < 5) stage(cur ^ 1, kk + 1);
        compute(cur);
        if (kk < 5) {
            asm volatile("s_waitcnt vmcnt(0)" ::: "memory");
            __builtin_amdgcn_s_barrier();
        }
    }

    // C/D layout (dtype-independent): col = lane&15, row = (lane>>4)*4 + reg
#pragma unroll
    for (int m = 0; m < 4; ++m) {
#pragma unroll
        for (int r = 0; r < 4; ++r) {
            const int rowg = jt * 128 + wr * 64 + m * 16 + lt * 4 + r;
            bool any = false;
#pragma unroll
            for (int n = 0; n < 4; ++n) {
                const int colg = it * 128 + wc * 64 + n * 16 + lr;
                any = any || (acc[m][n][r] > THRESH && rowg != colg);
            }
            if (any) bad[b * TN + rowg] = 1;   // benign race: all writers store 1
        }
    }
    if (!diag) {   // symmetry: flag columns too (their row view is this tile^T)
#pragma unroll
        for (int n = 0; n < 4; ++n) {
            const int colg = it * 128 + wc * 64 + n * 16 + lr;
            bool any = false;
#pragma unroll
            for (int m = 0; m < 4; ++m)
#pragma unroll
                for (int r = 0; r < 4; ++r)
                    any = any || (acc[m][n][r] > THRESH);
            if (any) bad[b * TN + colg] = 1;
        }
    }
}

// ---- K3: keep-count, top-k fallback (rank w/ index tiebreak), compaction ----
__global__ __launch_bounds__(256) void k_filter(const int* __restrict__ bad,
                                                const float* __restrict__ norms,
                                                int* __restrict__ inv,
                                                int* __restrict__ counts,
                                                int* __restrict__ Lval) {
    const int b = blockIdx.x, t = threadIdx.x;
    __shared__ float nsh[TN];
    __shared__ unsigned char ksh[TN];
    __shared__ int scan[256];

    for (int j = t; j < TN; j += 256) nsh[j] = norms[b * TN + j];
    const int j0 = t * 3;
#pragma unroll
    for (int q = 0; q < 3; ++q) ksh[j0 + q] = bad[b * TN + j0 + q] ? 0 : 1;
    __syncthreads();

    for (int round = 0; round < 2; ++round) {
        int local = ksh[j0] + ksh[j0 + 1] + ksh[j0 + 2];
        scan[t] = local;
        __syncthreads();
        for (int off = 1; off < 256; off <<= 1) {
            int v = (t >= off) ? scan[t - off] : 0;
            __syncthreads();
            scan[t] += v;
            __syncthreads();
        }
        int total = scan[255];
        if (round == 0 && total < POOL) {
            for (int q = 0; q < 3; ++q) {
                int j = j0 + q;
                float nj = nsh[j];
                int rank = 0;
                for (int i = 0; i < TN; ++i) {
                    float ni = nsh[i];
                    rank += (ni > nj) || (ni == nj && i < j);
                }
                ksh[j] = (rank < POOL) ? 1 : 0;
            }
            __syncthreads();
            continue;
        }
        int pos = scan[t] - local;
        for (int q = 0; q < 3; ++q) {
            int j = j0 + q;
            if (ksh[j]) inv[b * TN + pos++] = j;
        }
        if (t == 0) { counts[b] = total; atomicMax(Lval, total); }
        break;
    }
}

// ---- K4: pooled row (only a < 51 needed) + LayerNorm + attr head dot ----
__device__ inline float block_sum(float v, volatile float* sred, int t) {
#pragma unroll
    for (int m = 1; m < 64; m <<= 1) v += __shfl_xor(v, m);
    if ((t & 63) == 0) sred[t >> 6] = v;
    __syncthreads();
    float r = sred[0] + sred[1] + sred[2] + sred[3];
    __syncthreads();
    return r;
}

__global__ __launch_bounds__(256) void k_head(const float* __restrict__ x,
                                              const int* __restrict__ inv,
                                              const int* __restrict__ counts,
                                              const int* __restrict__ Lval,
                                              const float* __restrict__ lng,
                                              const float* __restrict__ lnb,
                                              const float* __restrict__ wat,
                                              const float* __restrict__ bat,
                                              float* __restrict__ logits) {
    const int a = blockIdx.x, b = blockIdx.y, t = threadIdx.x;
    __shared__ float sred[4];
    const int L = *Lval, cnt = counts[b];
    const int start = (a * L) >> 7;
    const int end = ((a + 1) * L + 127) >> 7;
    const int wdt = end - start;
    const int pe = min(end, cnt);

    float a0 = 0.f, a1 = 0.f, a2 = 0.f;
    for (int p = start; p < pe; ++p) {
        const float* row = x + (size_t)(b * TN + inv[b * TN + p]) * DIM;
        a0 += row[t]; a1 += row[t + 256]; a2 += row[t + 512];
    }
    const float iw = 1.0f / (float)wdt;
    a0 *= iw; a1 *= iw; a2 *= iw;

    float s1 = block_sum(a0 + a1 + a2, sred, t);
    float s2 = block_sum(a0 * a0 + a1 * a1 + a2 * a2, sred, t);
    const float mu = s1 * (1.0f / 768.0f);
    const float var = s2 * (1.0f / 768.0f) - mu * mu;
    const float rstd = rsqrtf(var + LNEPS);

    const float* wa = wat + (size_t)a * DIM;
    float d = ((a0 - mu) * rstd * lng[t]       + lnb[t])       * wa[t]
            + ((a1 - mu) * rstd * lng[t + 256] + lnb[t + 256]) * wa[t + 256]
            + ((a2 - mu) * rstd * lng[t + 512] + lnb[t + 512]) * wa[t + 512];
    float dot = block_sum(d, sred, t);
    if (t == 0) logits[b * NA + a] = dot + bat[a];
}

// ---------------- K5: BatchNorm1d over batch (training stats) ----------------
__global__ __launch_bounds__(64) void k_bn(const float* __restrict__ logits,
                                           const float* __restrict__ bng,
                                           const float* __restrict__ bnb,
                                           float* __restrict__ out) {
    const int a = threadIdx.x;
    if (a >= NA) return;
    float s = 0.f, s2 = 0.f;
    for (int b = 0; b < NB; ++b) {
        float v = logits[b * NA + a];
        s += v; s2 += v * v;
    }
    const float m = s * (1.0f / 64.0f);
    const float var = s2 * (1.0f / 64.0f) - m * m;
    const float rstd = rsqrtf(var + LNEPS);
    const float ga = bng[a], be = bnb[a];
    for (int b = 0; b < NB; ++b)
        out[b * NA + a] = (logits[b * NA + a] - m) * rstd * ga + be;
}

extern "C" void kernel_launch(void* const* d_in, const int* in_sizes, int n_in,
                              void* d_out, int out_size, void* d_ws, size_t ws_size,
                              hipStream_t stream) {
    const float* x     = (const float*)d_in[0];
    const float* ln_g  = (const float*)d_in[1];
    const float* ln_b  = (const float*)d_in[2];
    const float* w_at  = (const float*)d_in[3];
    const float* b_at  = (const float*)d_in[4];
    const float* bn_g  = (const float*)d_in[5];
    const float* bn_b  = (const float*)d_in[6];
    float* out = (float*)d_out;

    char* wsc = (char*)d_ws;
    const size_t XN = 64ull * 768 * 768;               // 37,748,736 B fp8 copy
    unsigned char* xn = (unsigned char*)wsc;
    float* norms  = (float*)(wsc + XN);                // 196608 B
    int*   bad    = (int*)(wsc + XN + 196608);         // 196608 B
    int*   inv    = (int*)(wsc + XN + 393216);         // 196608 B
    int*   counts = (int*)(wsc + XN + 589824);         // 256 B
    int*   Lval   = (int*)(wsc + XN + 590080);         // 256 B
    float* logits = (float*)(wsc + XN + 590336);       // 13056 B

    k_norms <<<NB * TN / 4, 256, 0, stream>>>(x, (unsigned int*)xn, norms, bad, Lval);
    k_gram  <<<21 * NB, 256, 0, stream>>>(xn, bad);
    k_filter<<<NB, 256, 0, stream>>>(bad, norms, inv, counts, Lval);
    k_head  <<<dim3(NA, NB), 256, 0, stream>>>(x, inv, counts, Lval,
                                               ln_g, ln_b, w_at, b_at, logits);
    k_bn    <<<1, 64, 0, stream>>>(logits, bn_g, bn_b, out);
}

// Round 7
// 78.622 us; speedup vs baseline: 2.0595x; 1.0180x over previous
//
#include <hip/hip_runtime.h>
#include <hip/hip_bf16.h>

#define TN 768
#define DIM 768
#define NB 64
#define NA 51
#define POOL 128
#define THRESH 0.75f
#define LNEPS 1e-5f

typedef float f32x4 __attribute__((ext_vector_type(4)));
typedef long l64x2 __attribute__((ext_vector_type(2)));

typedef const __attribute__((address_space(1))) unsigned int* gas_p;
typedef __attribute__((address_space(3))) unsigned int* las_p;

__device__ __forceinline__ void gload16(const void* g, void* l) {
    // dest = lds base + lane*16 (wave-uniform base); src is per-lane
    __builtin_amdgcn_global_load_lds((gas_p)g, (las_p)l, 16, 0, 0);
}

__constant__ int PAIR_I[21] = {0,1,1,2,2,2,3,3,3,3,4,4,4,4,4,5,5,5,5,5,5};
__constant__ int PAIR_J[21] = {0,0,1,0,1,2,0,1,2,3,0,1,2,3,4,0,1,2,3,4,5};

// ---- K1: per-token L2 norm + normalized fp8(e4m3) copy, PERMUTED layout ----
// Within each 128B k-block: source byte kb = 32c+8s+r  (c=K32 chunk, s=lane
// group slot, r in-slot) is stored at pos = 16*(4*(c>>1)+s) + 8*(c&1) + r.
// => LDS granule g = 4q+s is one ds_read_b128: lo 8B = chunk 2q, hi = 2q+1,
//    both for lane-group s. Also zeroes bad[] and Lval.
__global__ __launch_bounds__(256) void k_norms(const float* __restrict__ x,
                                               unsigned int* __restrict__ xn,
                                               float* __restrict__ norms,
                                               int* __restrict__ bad,
                                               int* __restrict__ Lval) {
    if (blockIdx.x < 192) bad[blockIdx.x * 256 + threadIdx.x] = 0;
    if (blockIdx.x == 0 && threadIdx.x == 0) *Lval = 0;

    const int tok  = blockIdx.x * 4 + (threadIdx.x >> 6);
    const int lane = threadIdx.x & 63;
    const float4* p = (const float4*)(x + (size_t)tok * DIM);
    float4 v[3];
    float s = 0.f;
#pragma unroll
    for (int q = 0; q < 3; ++q) {
        v[q] = p[q * 64 + lane];
        s += v[q].x * v[q].x + v[q].y * v[q].y + v[q].z * v[q].z + v[q].w * v[q].w;
    }
#pragma unroll
    for (int m = 1; m < 64; m <<= 1) s += __shfl_xor(s, m);
    const float nrm = sqrtf(s);
    const float sc = 1.0f / nrm;
    unsigned int* xrow = xn + (size_t)tok * 192;        // 768 B / 4
#pragma unroll
    for (int q = 0; q < 3; ++q) {
        int w0 = __builtin_amdgcn_cvt_pk_fp8_f32(v[q].x * sc, v[q].y * sc, 0, false);
        w0     = __builtin_amdgcn_cvt_pk_fp8_f32(v[q].z * sc, v[q].w * sc, w0, true);
        const int k  = q * 256 + lane * 4;              // byte index in row
        const int kb = k & 127;
        const int c  = kb >> 5, sl = (kb >> 3) & 3, r = kb & 7;
        const int pos = (k & ~127) + 16 * (4 * (c >> 1) + sl) + 8 * (c & 1) + r;
        xrow[pos >> 2] = (unsigned)w0;
    }
    if (lane == 0) norms[tok] = nrm;
}

// ---- K2: fp8 gram tiles, triangle (21 pairs), 2-phase dbuf, 64x64 wave tiles ----
// 256 thr (2x2 wave grid), 64 KB LDS (2 blocks/CU), 6 K-steps of 128 fp8.
__global__ __launch_bounds__(256) void k_gram(const unsigned char* __restrict__ xn,
                                              int* __restrict__ bad) {
    // bijective XCD swizzle: 1344 blocks = 8 XCD x 168
    const int f = blockIdx.x;
    const int lid = (f & 7) * 168 + (f >> 3);
    const int b = lid / 21, p = lid - b * 21;
    const int it = PAIR_I[p], jt = PAIR_J[p];
    const bool diag = (it == jt);

    const int tid = threadIdx.x;
    const int lane = tid & 63, w = tid >> 6;
    const int lr = lane & 15, lt = lane >> 4;
    const int wr = w >> 1, wc = w & 1;                  // 2x2 wave grid

    __shared__ alignas(16) unsigned char lA[2][128 * 128];   // 2 x 16 KB
    __shared__ alignas(16) unsigned char lB[2][128 * 128];

    const unsigned char* xb = xn + (size_t)b * TN * DIM;     // 768 B / token
    // stage: 1KB LDS segment = 8 rows x 128B; lane l -> row (l>>3), granule
    // (l&7). LDS[row][g] = SRC[row][g ^ (row&7)]  (pre-swizzled source,
    // linear dest -- rule #21). Compute reads granule (4q+lt)^(row&7) -> the
    // content is source granule 4q+lt = permuted (q, slot=lt) pair.
    const int srow = lane >> 3;
    const int sgoff = 16 * ((lane & 7) ^ (srow & 7));
    const size_t baseA = (size_t)(jt * 128 + srow) * DIM + sgoff;
    const size_t baseB = (size_t)(it * 128 + srow) * DIM + sgoff;

    f32x4 acc[4][4];
#pragma unroll
    for (int m = 0; m < 4; ++m)
#pragma unroll
        for (int n = 0; n < 4; ++n) acc[m][n] = {0.f, 0.f, 0.f, 0.f};

    auto stage = [&](int bb, int kk) {
#pragma unroll
        for (int i = 0; i < 4; ++i) {            // 4 segs/wave = 16 segs = 16 KB
            const int seg = w * 4 + i;
            gload16(xb + baseA + (size_t)seg * 8 * DIM + kk * 128,
                    (char*)lA[bb] + seg * 1024);
        }
        if (!diag) {
#pragma unroll
            for (int i = 0; i < 4; ++i) {
                const int seg = w * 4 + i;
                gload16(xb + baseB + (size_t)seg * 8 * DIM + kk * 128,
                        (char*)lB[bb] + seg * 1024);
            }
        }
    };

    auto compute = [&](int bb) {
        const unsigned char* As = lA[bb];
        const unsigned char* Bs = diag ? lA[bb] : lB[bb];
        const int gx = lr & 7;
#pragma unroll
        for (int q = 0; q < 2; ++q) {
            const int goff = 16 * ((4 * q + lt) ^ gx);
            l64x2 a[4], bv[4];
#pragma unroll
            for (int m = 0; m < 4; ++m)
                a[m] = *(const l64x2*)&As[(wr * 64 + m * 16 + lr) * 128 + goff];
#pragma unroll
            for (int n = 0; n < 4; ++n)
                bv[n] = *(const l64x2*)&Bs[(wc * 64 + n * 16 + lr) * 128 + goff];
#pragma unroll
            for (int m = 0; m < 4; ++m)
#pragma unroll
                for (int n = 0; n < 4; ++n) {
                    acc[m][n] = __builtin_amdgcn_mfma_f32_16x16x32_fp8_fp8(a[m][0], bv[n][0], acc[m][n], 0, 0, 0);
                    acc[m][n] = __builtin_amdgcn_mfma_f32_16x16x32_fp8_fp8(a[m][1], bv[n][1], acc[m][n], 0, 0, 0);
                }
        }
    };

    // 2-phase pipeline: stage(next) || compute(cur); one vmcnt(0)+barrier/step
    stage(0, 0);
    asm volatile("s_waitcnt vmcnt(0)" ::: "memory");
    __builtin_amdgcn_s_barrier();
#pragma unroll
    for (int kk = 0; kk < 6; ++kk) {
        const int cur = kk & 1;
        if (kk < 5) stage(cur ^ 1, kk + 1);
        compute(cur);
        if (kk < 5) {
            asm volatile("s_waitcnt vmcnt(0)" ::: "memory");
            __builtin_amdgcn_s_barrier();
        }
    }

    // C/D layout (dtype-independent): col = lane&15, row = (lane>>4)*4 + reg
#pragma unroll
    for (int m = 0; m < 4; ++m) {
#pragma unroll
        for (int r = 0; r < 4; ++r) {
            const int rowg = jt * 128 + wr * 64 + m * 16 + lt * 4 + r;
            bool any = false;
#pragma unroll
            for (int n = 0; n < 4; ++n) {
                const int colg = it * 128 + wc * 64 + n * 16 + lr;
                any = any || (acc[m][n][r] > THRESH && rowg != colg);
            }
            if (any) bad[b * TN + rowg] = 1;   // benign race: all writers store 1
        }
    }
    if (!diag) {   // symmetry: flag columns too (their row view is this tile^T)
#pragma unroll
        for (int n = 0; n < 4; ++n) {
            const int colg = it * 128 + wc * 64 + n * 16 + lr;
            bool any = false;
#pragma unroll
            for (int m = 0; m < 4; ++m)
#pragma unroll
                for (int r = 0; r < 4; ++r)
                    any = any || (acc[m][n][r] > THRESH);
            if (any) bad[b * TN + colg] = 1;
        }
    }
}

// ---- K3: ballot-based keep/compaction (+ top-k fallback, rank w/ tiebreak) ----
// Thread t (wave w, lane l) owns tokens q*256 + w*64 + l (q=0..2) -> keep-mask
// word 4q+w. Stable compaction position = popcount prefix over mask words.
__global__ __launch_bounds__(256) void k_filter(const int* __restrict__ bad,
                                                const float* __restrict__ norms,
                                                int* __restrict__ inv,
                                                int* __restrict__ counts,
                                                int* __restrict__ Lval) {
    const int b = blockIdx.x, t = threadIdx.x;
    const int w = t >> 6, l = t & 63;
    __shared__ unsigned long long kw[12];
    __shared__ float nsh[TN];

    bool kp[3];
#pragma unroll
    for (int q = 0; q < 3; ++q)
        kp[q] = (bad[b * TN + q * 256 + w * 64 + l] == 0);
#pragma unroll
    for (int q = 0; q < 3; ++q) {
        unsigned long long m = __ballot(kp[q]);
        if (l == 0) kw[4 * q + w] = m;
    }
    __syncthreads();
    int total = 0;
    for (int i = 0; i < 12; ++i) total += __popcll(kw[i]);

    if (total < POOL) {
        // fallback: top-128 by norm, ties -> lower index (matches lax.top_k)
        for (int j = t; j < TN; j += 256) nsh[j] = norms[b * TN + j];
        __syncthreads();
#pragma unroll
        for (int q = 0; q < 3; ++q) {
            const int j = q * 256 + w * 64 + l;
            const float nj = nsh[j];
            int rank = 0;
            for (int i = 0; i < TN; ++i) {
                float ni = nsh[i];
                rank += (ni > nj) || (ni == nj && i < j);
            }
            kp[q] = (rank < POOL);
        }
        __syncthreads();          // kw rewrite hazard
#pragma unroll
        for (int q = 0; q < 3; ++q) {
            unsigned long long m = __ballot(kp[q]);
            if (l == 0) kw[4 * q + w] = m;
        }
        __syncthreads();
        total = 0;
        for (int i = 0; i < 12; ++i) total += __popcll(kw[i]);
    }

    // stable scatter via popcount prefix (loop bound is runtime: no array idx)
#pragma unroll
    for (int q = 0; q < 3; ++q) {
        if (kp[q]) {
            const int W = 4 * q + w;
            int pos = __popcll(kw[W] & ((1ull << l) - 1ull));
            for (int i = 0; i < W; ++i) pos += __popcll(kw[i]);
            inv[b * TN + pos] = q * 256 + w * 64 + l;
        }
    }
    if (t == 0) { counts[b] = total; atomicMax(Lval, total); }
}

// ---- K4: pooled row (only a < 51 needed) + LayerNorm + attr head dot ----
// float4 per thread: threads 0..191 own cols 4t..4t+3 (col->thread map is
// arbitrary for LN sums and the dot; only coverage matters).
__device__ inline float block_sum(float v, volatile float* sred, int t) {
#pragma unroll
    for (int m = 1; m < 64; m <<= 1) v += __shfl_xor(v, m);
    if ((t & 63) == 0) sred[t >> 6] = v;
    __syncthreads();
    float r = sred[0] + sred[1] + sred[2] + sred[3];
    __syncthreads();
    return r;
}

__global__ __launch_bounds__(256) void k_head(const float* __restrict__ x,
                                              const int* __restrict__ inv,
                                              const int* __restrict__ counts,
                                              const int* __restrict__ Lval,
                                              const float* __restrict__ lng,
                                              const float* __restrict__ lnb,
                                              const float* __restrict__ wat,
                                              const float* __restrict__ bat,
                                              float* __restrict__ logits) {
    const int a = blockIdx.x, b = blockIdx.y, t = threadIdx.x;
    __shared__ float sred[4];
    const int L = *Lval, cnt = counts[b];
    const int start = (a * L) >> 7;
    const int end = ((a + 1) * L + 127) >> 7;
    const int wdt = end - start;
    const int pe = min(end, cnt);

    float4 s4 = {0.f, 0.f, 0.f, 0.f};
    if (t < 192) {
        for (int p = start; p < pe; ++p) {
            const float4* row = (const float4*)(x + (size_t)(b * TN + inv[b * TN + p]) * DIM);
            float4 v = row[t];
            s4.x += v.x; s4.y += v.y; s4.z += v.z; s4.w += v.w;
        }
    }
    const float iw = 1.0f / (float)wdt;
    s4.x *= iw; s4.y *= iw; s4.z *= iw; s4.w *= iw;

    float s1 = block_sum(s4.x + s4.y + s4.z + s4.w, sred, t);
    float s2 = block_sum(s4.x * s4.x + s4.y * s4.y + s4.z * s4.z + s4.w * s4.w, sred, t);
    const float mu = s1 * (1.0f / 768.0f);
    const float var = s2 * (1.0f / 768.0f) - mu * mu;
    const float rstd = rsqrtf(var + LNEPS);

    float d = 0.f;
    if (t < 192) {
        const float4 g  = ((const float4*)lng)[t];
        const float4 be = ((const float4*)lnb)[t];
        const float4 wv = ((const float4*)(wat + (size_t)a * DIM))[t];
        d = ((s4.x - mu) * rstd * g.x + be.x) * wv.x
          + ((s4.y - mu) * rstd * g.y + be.y) * wv.y
          + ((s4.z - mu) * rstd * g.z + be.z) * wv.z
          + ((s4.w - mu) * rstd * g.w + be.w) * wv.w;
    }
    float dot = block_sum(d, sred, t);
    if (t == 0) logits[b * NA + a] = dot + bat[a];
}

// ---------------- K5: BatchNorm1d over batch (training stats) ----------------
__global__ __launch_bounds__(64) void k_bn(const float* __restrict__ logits,
                                           const float* __restrict__ bng,
                                           const float* __restrict__ bnb,
                                           float* __restrict__ out) {
    const int a = threadIdx.x;
    if (a >= NA) return;
    float s = 0.f, s2 = 0.f;
    for (int b = 0; b < NB; ++b) {
        float v = logits[b * NA + a];
        s += v; s2 += v * v;
    }
    const float m = s * (1.0f / 64.0f);
    const float var = s2 * (1.0f / 64.0f) - m * m;
    const float rstd = rsqrtf(var + LNEPS);
    const float ga = bng[a], be = bnb[a];
    for (int b = 0; b < NB; ++b)
        out[b * NA + a] = (logits[b * NA + a] - m) * rstd * ga + be;
}

extern "C" void kernel_launch(void* const* d_in, const int* in_sizes, int n_in,
                              void* d_out, int out_size, void* d_ws, size_t ws_size,
                              hipStream_t stream) {
    const float* x     = (const float*)d_in[0];
    const float* ln_g  = (const float*)d_in[1];
    const float* ln_b  = (const float*)d_in[2];
    const float* w_at  = (const float*)d_in[3];
    const float* b_at  = (const float*)d_in[4];
    const float* bn_g  = (const float*)d_in[5];
    const float* bn_b  = (const float*)d_in[6];
    float* out = (float*)d_out;

    char* wsc = (char*)d_ws;
    const size_t XN = 64ull * 768 * 768;               // 37,748,736 B fp8 copy
    unsigned char* xn = (unsigned char*)wsc;
    float* norms  = (float*)(wsc + XN);                // 196608 B
    int*   bad    = (int*)(wsc + XN + 196608);         // 196608 B
    int*   inv    = (int*)(wsc + XN + 393216);         // 196608 B
    int*   counts = (int*)(wsc + XN + 589824);         // 256 B
    int*   Lval   = (int*)(wsc + XN + 590080);         // 256 B
    float* logits = (float*)(wsc + XN + 590336);       // 13056 B

    k_norms <<<NB * TN / 4, 256, 0, stream>>>(x, (unsigned int*)xn, norms, bad, Lval);
    k_gram  <<<21 * NB, 256, 0, stream>>>(xn, bad);
    k_filter<<<NB, 256, 0, stream>>>(bad, norms, inv, counts, Lval);
    k_head  <<<dim3(NA, NB), 256, 0, stream>>>(x, inv, counts, Lval,
                                               ln_g, ln_b, w_at, b_at, logits);
    k_bn    <<<1, 64, 0, stream>>>(logits, bn_g, bn_b, out);
}

// Round 8
// 76.981 us; speedup vs baseline: 2.1034x; 1.0213x over previous
//
#include <hip/hip_runtime.h>
#include <hip/hip_bf16.h>

#define TN 768
#define DIM 768
#define NB 64
#define NA 51
#define POOL 128
#define THRESH 0.75f
#define LNEPS 1e-5f

typedef float f32x4 __attribute__((ext_vector_type(4)));
typedef long l64x2 __attribute__((ext_vector_type(2)));

typedef const __attribute__((address_space(1))) unsigned int* gas_p;
typedef __attribute__((address_space(3))) unsigned int* las_p;

__device__ __forceinline__ void gload16(const void* g, void* l) {
    // dest = lds base + lane*16 (wave-uniform base); src is per-lane
    __builtin_amdgcn_global_load_lds((gas_p)g, (las_p)l, 16, 0, 0);
}

__constant__ int PAIR_I[21] = {0,1,1,2,2,2,3,3,3,3,4,4,4,4,4,5,5,5,5,5,5};
__constant__ int PAIR_J[21] = {0,0,1,0,1,2,0,1,2,3,0,1,2,3,4,0,1,2,3,4,5};

// ---- K1: per-token L2 norm + normalized fp8(e4m3) copy, PERMUTED layout ----
// Within each 128B k-block: source byte kb = 32c+8s+r  (c=K32 chunk, s=lane
// group slot, r in-slot) is stored at pos = 16*(4*(c>>1)+s) + 8*(c&1) + r.
// => LDS granule g = 4q+s is one ds_read_b128: lo 8B = chunk 2q, hi = 2q+1,
//    both for lane-group s. Also zeroes bad[] and Lval.
__global__ __launch_bounds__(256) void k_norms(const float* __restrict__ x,
                                               unsigned int* __restrict__ xn,
                                               float* __restrict__ norms,
                                               int* __restrict__ bad,
                                               int* __restrict__ Lval) {
    if (blockIdx.x < 192) bad[blockIdx.x * 256 + threadIdx.x] = 0;
    if (blockIdx.x == 0 && threadIdx.x == 0) *Lval = 0;

    const int tok  = blockIdx.x * 4 + (threadIdx.x >> 6);
    const int lane = threadIdx.x & 63;
    const float4* p = (const float4*)(x + (size_t)tok * DIM);
    float4 v[3];
    float s = 0.f;
#pragma unroll
    for (int q = 0; q < 3; ++q) {
        v[q] = p[q * 64 + lane];
        s += v[q].x * v[q].x + v[q].y * v[q].y + v[q].z * v[q].z + v[q].w * v[q].w;
    }
#pragma unroll
    for (int m = 1; m < 64; m <<= 1) s += __shfl_xor(s, m);
    const float nrm = sqrtf(s);
    const float sc = 1.0f / nrm;
    unsigned int* xrow = xn + (size_t)tok * 192;        // 768 B / 4
#pragma unroll
    for (int q = 0; q < 3; ++q) {
        int w0 = __builtin_amdgcn_cvt_pk_fp8_f32(v[q].x * sc, v[q].y * sc, 0, false);
        w0     = __builtin_amdgcn_cvt_pk_fp8_f32(v[q].z * sc, v[q].w * sc, w0, true);
        const int k  = q * 256 + lane * 4;              // byte index in row
        const int kb = k & 127;
        const int c  = kb >> 5, sl = (kb >> 3) & 3, r = kb & 7;
        const int pos = (k & ~127) + 16 * (4 * (c >> 1) + sl) + 8 * (c & 1) + r;
        xrow[pos >> 2] = (unsigned)w0;
    }
    if (lane == 0) norms[tok] = nrm;
}

// ---- K2: fp8 gram tiles, triangle (21 pairs), 2-phase dbuf, 64x64 wave tiles ----
// 256 thr (2x2 wave grid), 64 KB LDS (2 blocks/CU), 6 K-steps of 128 fp8.
__global__ __launch_bounds__(256) void k_gram(const unsigned char* __restrict__ xn,
                                              int* __restrict__ bad) {
    // bijective XCD swizzle: 1344 blocks = 8 XCD x 168
    const int f = blockIdx.x;
    const int lid = (f & 7) * 168 + (f >> 3);
    const int b = lid / 21, p = lid - b * 21;
    const int it = PAIR_I[p], jt = PAIR_J[p];
    const bool diag = (it == jt);

    const int tid = threadIdx.x;
    const int lane = tid & 63, w = tid >> 6;
    const int lr = lane & 15, lt = lane >> 4;
    const int wr = w >> 1, wc = w & 1;                  // 2x2 wave grid

    __shared__ alignas(16) unsigned char lA[2][128 * 128];   // 2 x 16 KB
    __shared__ alignas(16) unsigned char lB[2][128 * 128];

    const unsigned char* xb = xn + (size_t)b * TN * DIM;     // 768 B / token
    // stage: 1KB LDS segment = 8 rows x 128B; lane l -> row (l>>3), granule
    // (l&7). LDS[row][g] = SRC[row][g ^ (row&7)]  (pre-swizzled source,
    // linear dest -- rule #21). Compute reads granule (4q+lt)^(row&7) -> the
    // content is source granule 4q+lt = permuted (q, slot=lt) pair.
    const int srow = lane >> 3;
    const int sgoff = 16 * ((lane & 7) ^ (srow & 7));
    const size_t baseA = (size_t)(jt * 128 + srow) * DIM + sgoff;
    const size_t baseB = (size_t)(it * 128 + srow) * DIM + sgoff;

    f32x4 acc[4][4];
#pragma unroll
    for (int m = 0; m < 4; ++m)
#pragma unroll
        for (int n = 0; n < 4; ++n) acc[m][n] = {0.f, 0.f, 0.f, 0.f};

    auto stage = [&](int bb, int kk) {
#pragma unroll
        for (int i = 0; i < 4; ++i) {            // 4 segs/wave = 16 segs = 16 KB
            const int seg = w * 4 + i;
            gload16(xb + baseA + (size_t)seg * 8 * DIM + kk * 128,
                    (char*)lA[bb] + seg * 1024);
        }
        if (!diag) {
#pragma unroll
            for (int i = 0; i < 4; ++i) {
                const int seg = w * 4 + i;
                gload16(xb + baseB + (size_t)seg * 8 * DIM + kk * 128,
                        (char*)lB[bb] + seg * 1024);
            }
        }
    };

    auto compute = [&](int bb) {
        const unsigned char* As = lA[bb];
        const unsigned char* Bs = diag ? lA[bb] : lB[bb];
        const int gx = lr & 7;
#pragma unroll
        for (int q = 0; q < 2; ++q) {
            const int goff = 16 * ((4 * q + lt) ^ gx);
            l64x2 a[4], bv[4];
#pragma unroll
            for (int m = 0; m < 4; ++m)
                a[m] = *(const l64x2*)&As[(wr * 64 + m * 16 + lr) * 128 + goff];
#pragma unroll
            for (int n = 0; n < 4; ++n)
                bv[n] = *(const l64x2*)&Bs[(wc * 64 + n * 16 + lr) * 128 + goff];
#pragma unroll
            for (int m = 0; m < 4; ++m)
#pragma unroll
                for (int n = 0; n < 4; ++n) {
                    acc[m][n] = __builtin_amdgcn_mfma_f32_16x16x32_fp8_fp8(a[m][0], bv[n][0], acc[m][n], 0, 0, 0);
                    acc[m][n] = __builtin_amdgcn_mfma_f32_16x16x32_fp8_fp8(a[m][1], bv[n][1], acc[m][n], 0, 0, 0);
                }
        }
    };

    // 2-phase pipeline: stage(next) || compute(cur); one vmcnt(0)+barrier/step
    stage(0, 0);
    asm volatile("s_waitcnt vmcnt(0)" ::: "memory");
    __builtin_amdgcn_s_barrier();
#pragma unroll
    for (int kk = 0; kk < 6; ++kk) {
        const int cur = kk & 1;
        if (kk < 5) stage(cur ^ 1, kk + 1);
        compute(cur);
        if (kk < 5) {
            asm volatile("s_waitcnt vmcnt(0)" ::: "memory");
            __builtin_amdgcn_s_barrier();
        }
    }

    // C/D layout (dtype-independent): col = lane&15, row = (lane>>4)*4 + reg
#pragma unroll
    for (int m = 0; m < 4; ++m) {
#pragma unroll
        for (int r = 0; r < 4; ++r) {
            const int rowg = jt * 128 + wr * 64 + m * 16 + lt * 4 + r;
            bool any = false;
#pragma unroll
            for (int n = 0; n < 4; ++n) {
                const int colg = it * 128 + wc * 64 + n * 16 + lr;
                any = any || (acc[m][n][r] > THRESH && rowg != colg);
            }
            if (any) bad[b * TN + rowg] = 1;   // benign race: all writers store 1
        }
    }
    if (!diag) {   // symmetry: flag columns too (their row view is this tile^T)
#pragma unroll
        for (int n = 0; n < 4; ++n) {
            const int colg = it * 128 + wc * 64 + n * 16 + lr;
            bool any = false;
#pragma unroll
            for (int m = 0; m < 4; ++m)
#pragma unroll
                for (int r = 0; r < 4; ++r)
                    any = any || (acc[m][n][r] > THRESH);
            if (any) bad[b * TN + colg] = 1;
        }
    }
}

// ---- K3: ballot-based keep/compaction (+ top-k fallback, rank w/ tiebreak) ----
__global__ __launch_bounds__(256) void k_filter(const int* __restrict__ bad,
                                                const float* __restrict__ norms,
                                                int* __restrict__ inv,
                                                int* __restrict__ counts,
                                                int* __restrict__ Lval) {
    const int b = blockIdx.x, t = threadIdx.x;
    const int w = t >> 6, l = t & 63;
    __shared__ unsigned long long kw[12];
    __shared__ float nsh[TN];

    bool kp[3];
#pragma unroll
    for (int q = 0; q < 3; ++q)
        kp[q] = (bad[b * TN + q * 256 + w * 64 + l] == 0);
#pragma unroll
    for (int q = 0; q < 3; ++q) {
        unsigned long long m = __ballot(kp[q]);
        if (l == 0) kw[4 * q + w] = m;
    }
    __syncthreads();
    int total = 0;
    for (int i = 0; i < 12; ++i) total += __popcll(kw[i]);

    if (total < POOL) {
        // fallback: top-128 by norm, ties -> lower index (matches lax.top_k)
        for (int j = t; j < TN; j += 256) nsh[j] = norms[b * TN + j];
        __syncthreads();
#pragma unroll
        for (int q = 0; q < 3; ++q) {
            const int j = q * 256 + w * 64 + l;
            const float nj = nsh[j];
            int rank = 0;
            for (int i = 0; i < TN; ++i) {
                float ni = nsh[i];
                rank += (ni > nj) || (ni == nj && i < j);
            }
            kp[q] = (rank < POOL);
        }
        __syncthreads();          // kw rewrite hazard
#pragma unroll
        for (int q = 0; q < 3; ++q) {
            unsigned long long m = __ballot(kp[q]);
            if (l == 0) kw[4 * q + w] = m;
        }
        __syncthreads();
        total = 0;
        for (int i = 0; i < 12; ++i) total += __popcll(kw[i]);
    }

    // stable scatter via popcount prefix
#pragma unroll
    for (int q = 0; q < 3; ++q) {
        if (kp[q]) {
            const int W = 4 * q + w;
            int pos = __popcll(kw[W] & ((1ull << l) - 1ull));
            for (int i = 0; i < W; ++i) pos += __popcll(kw[i]);
            inv[b * TN + pos] = q * 256 + w * 64 + l;
        }
    }
    if (t == 0) { counts[b] = total; atomicMax(Lval, total); }
}

// ---- K4: pooled row (only a < 51 needed) + LayerNorm + attr head dot ----
// 192 threads (3 waves); thread t owns cols 4t..4t+3. Bin width <= 7 and
// uniform per block -> gather inv[] first, then issue ALL row loads
// back-to-back (independent) to pay ONE memory latency, not ~6 serial ones.
__device__ inline float block_sum3(float v, volatile float* sred, int t) {
#pragma unroll
    for (int m = 1; m < 64; m <<= 1) v += __shfl_xor(v, m);
    if ((t & 63) == 0) sred[t >> 6] = v;
    __syncthreads();
    float r = sred[0] + sred[1] + sred[2];
    __syncthreads();
    return r;
}

__global__ __launch_bounds__(192) void k_head(const float* __restrict__ x,
                                              const int* __restrict__ inv,
                                              const int* __restrict__ counts,
                                              const int* __restrict__ Lval,
                                              const float* __restrict__ lng,
                                              const float* __restrict__ lnb,
                                              const float* __restrict__ wat,
                                              const float* __restrict__ bat,
                                              float* __restrict__ logits) {
    const int a = blockIdx.x, b = blockIdx.y, t = threadIdx.x;
    __shared__ float sred[3];
    const int L = *Lval, cnt = counts[b];
    const int start = (a * L) >> 7;
    const int end = ((a + 1) * L + 127) >> 7;
    const int wdt = end - start;                 // <= floor(L/128)+1 <= 7
    const int pe = min(end, cnt);
    const int nv = pe - start;                   // block-uniform, 0..7

    int idx[7];
#pragma unroll
    for (int i = 0; i < 7; ++i)
        idx[i] = (i < nv) ? inv[b * TN + start + i] : 0;

    float4 v[7];
#pragma unroll
    for (int i = 0; i < 7; ++i)
        if (i < nv)                              // uniform branch, loads overlap
            v[i] = ((const float4*)(x + (size_t)(b * TN + idx[i]) * DIM))[t];

    float4 s4 = {0.f, 0.f, 0.f, 0.f};
#pragma unroll
    for (int i = 0; i < 7; ++i)
        if (i < nv) {
            s4.x += v[i].x; s4.y += v[i].y; s4.z += v[i].z; s4.w += v[i].w;
        }
    const float iw = 1.0f / (float)wdt;
    s4.x *= iw; s4.y *= iw; s4.z *= iw; s4.w *= iw;

    float s1 = block_sum3(s4.x + s4.y + s4.z + s4.w, sred, t);
    float s2 = block_sum3(s4.x * s4.x + s4.y * s4.y + s4.z * s4.z + s4.w * s4.w, sred, t);
    const float mu = s1 * (1.0f / 768.0f);
    const float var = s2 * (1.0f / 768.0f) - mu * mu;
    const float rstd = rsqrtf(var + LNEPS);

    const float4 g  = ((const float4*)lng)[t];
    const float4 be = ((const float4*)lnb)[t];
    const float4 wv = ((const float4*)(wat + (size_t)a * DIM))[t];
    float d = ((s4.x - mu) * rstd * g.x + be.x) * wv.x
            + ((s4.y - mu) * rstd * g.y + be.y) * wv.y
            + ((s4.z - mu) * rstd * g.z + be.z) * wv.z
            + ((s4.w - mu) * rstd * g.w + be.w) * wv.w;
    float dot = block_sum3(d, sred, t);
    if (t == 0) logits[b * NA + a] = dot + bat[a];
}

// ---------------- K5: BatchNorm1d over batch (training stats) ----------------
__global__ __launch_bounds__(64) void k_bn(const float* __restrict__ logits,
                                           const float* __restrict__ bng,
                                           const float* __restrict__ bnb,
                                           float* __restrict__ out) {
    const int a = threadIdx.x;
    if (a >= NA) return;
    float s = 0.f, s2 = 0.f;
    for (int b = 0; b < NB; ++b) {
        float v = logits[b * NA + a];
        s += v; s2 += v * v;
    }
    const float m = s * (1.0f / 64.0f);
    const float var = s2 * (1.0f / 64.0f) - m * m;
    const float rstd = rsqrtf(var + LNEPS);
    const float ga = bng[a], be = bnb[a];
    for (int b = 0; b < NB; ++b)
        out[b * NA + a] = (logits[b * NA + a] - m) * rstd * ga + be;
}

extern "C" void kernel_launch(void* const* d_in, const int* in_sizes, int n_in,
                              void* d_out, int out_size, void* d_ws, size_t ws_size,
                              hipStream_t stream) {
    const float* x     = (const float*)d_in[0];
    const float* ln_g  = (const float*)d_in[1];
    const float* ln_b  = (const float*)d_in[2];
    const float* w_at  = (const float*)d_in[3];
    const float* b_at  = (const float*)d_in[4];
    const float* bn_g  = (const float*)d_in[5];
    const float* bn_b  = (const float*)d_in[6];
    float* out = (float*)d_out;

    char* wsc = (char*)d_ws;
    const size_t XN = 64ull * 768 * 768;               // 37,748,736 B fp8 copy
    unsigned char* xn = (unsigned char*)wsc;
    float* norms  = (float*)(wsc + XN);                // 196608 B
    int*   bad    = (int*)(wsc + XN + 196608);         // 196608 B
    int*   inv    = (int*)(wsc + XN + 393216);         // 196608 B
    int*   counts = (int*)(wsc + XN + 589824);         // 256 B
    int*   Lval   = (int*)(wsc + XN + 590080);         // 256 B
    float* logits = (float*)(wsc + XN + 590336);       // 13056 B

    k_norms <<<NB * TN / 4, 256, 0, stream>>>(x, (unsigned int*)xn, norms, bad, Lval);
    k_gram  <<<21 * NB, 256, 0, stream>>>(xn, bad);
    k_filter<<<NB, 256, 0, stream>>>(bad, norms, inv, counts, Lval);
    k_head  <<<dim3(NA, NB), 192, 0, stream>>>(x, inv, counts, Lval,
                                               ln_g, ln_b, w_at, b_at, logits);
    k_bn    <<<1, 64, 0, stream>>>(logits, bn_g, bn_b, out);
}